// Round 1
// baseline (976.984 us; speedup 1.0000x reference)
//
#include <hip/hip_runtime.h>
#include <hip/hip_bf16.h>
#include <cstdint>

#define DH 256   // hidden dims (both layers)
#define DIN 512
#define DOUT 64

// ---------------- edge_index dtype detection ----------------
// If the buffer really holds int64 indices, every 8-byte word is < N.
// If it holds int32, an 8-byte view mixes two indices -> huge values.
__global__ void detect_i64(const unsigned long long* ei, int n_check,
                           unsigned long long bound, int* flag) {
    __shared__ int ok;
    if (threadIdx.x == 0) ok = 1;
    __syncthreads();
    int bad = 0;
    for (int i = threadIdx.x; i < n_check; i += blockDim.x) {
        if (ei[i] >= bound) bad = 1;
    }
    if (bad) ok = 0;          // benign race: all writers store 0
    __syncthreads();
    if (threadIdx.x == 0) *flag = ok;
}

__device__ __forceinline__ int get_idx(const void* ei, int is64, int pos) {
    if (is64) return (int)((const long long*)ei)[pos];
    return ((const int*)ei)[pos];
}

// ---------------- degree count ----------------
__global__ void count_deg(const void* ei, const int* flag, int E, int* counts) {
    const int is64 = *flag;
    int e = blockIdx.x * blockDim.x + threadIdx.x;
    if (e >= E) return;
    int d = get_idx(ei, is64, E + e);   // dst row
    atomicAdd(&counts[d], 1);
}

__global__ void compute_dinv(const int* counts, float* dinv, int N) {
    int i = blockIdx.x * blockDim.x + threadIdx.x;
    if (i < N) dinv[i] = rsqrtf((float)counts[i] + 1.0f);
}

// ---------------- exclusive scan (3-kernel) ----------------
#define SCAN_BLOCK 256
#define SCAN_ELEMS 1024

__global__ void scan1(const int* counts, int* out, int* blocksums, int N) {
    __shared__ int sh[SCAN_BLOCK];
    int base = blockIdx.x * SCAN_ELEMS;
    int t = threadIdx.x;
    int v[4];
    int s = 0;
    #pragma unroll
    for (int j = 0; j < 4; j++) {
        int idx = base + t * 4 + j;
        v[j] = (idx < N) ? counts[idx] : 0;
        s += v[j];
    }
    sh[t] = s;
    __syncthreads();
    for (int off = 1; off < SCAN_BLOCK; off <<= 1) {
        int x = (t >= off) ? sh[t - off] : 0;
        __syncthreads();
        sh[t] += x;
        __syncthreads();
    }
    int run = (t == 0) ? 0 : sh[t - 1];
    #pragma unroll
    for (int j = 0; j < 4; j++) {
        int idx = base + t * 4 + j;
        if (idx < N) out[idx] = run;
        run += v[j];
    }
    if (t == SCAN_BLOCK - 1) blocksums[blockIdx.x] = sh[t];
}

__global__ void scan2(int* blocksums, int NB) {
    __shared__ int sh[SCAN_BLOCK];
    int t = threadIdx.x;
    sh[t] = (t < NB) ? blocksums[t] : 0;
    __syncthreads();
    for (int off = 1; off < SCAN_BLOCK; off <<= 1) {
        int x = (t >= off) ? sh[t - off] : 0;
        __syncthreads();
        sh[t] += x;
        __syncthreads();
    }
    if (t < NB) blocksums[t] = (t == 0) ? 0 : sh[t - 1];
}

__global__ void scan3(int* row_ptr, const int* blocksums, int N, int E) {
    int i = blockIdx.x * blockDim.x + threadIdx.x;
    if (i < N) row_ptr[i] += blocksums[i / SCAN_ELEMS];
    if (i == N) row_ptr[N] = E;
}

// ---------------- CSR fill ----------------
__global__ void fill_csr(const void* ei, const int* flag, int E,
                         const int* row_ptr, int* cursor, int* col_idx) {
    const int is64 = *flag;
    int e = blockIdx.x * blockDim.x + threadIdx.x;
    if (e >= E) return;
    int d = get_idx(ei, is64, E + e);
    int s = get_idx(ei, is64, e);
    int pos = row_ptr[d] + atomicAdd(&cursor[d], 1);
    col_idx[pos] = s;
}

// ---------------- fp32 tiled GEMM: C[M,N] = A[M,K] @ B[K,N] (+bias) ----------------
template <bool BIAS>
__global__ __launch_bounds__(256) void gemm(const float* __restrict__ A,
                                            const float* __restrict__ B,
                                            const float* __restrict__ bias,
                                            float* __restrict__ C,
                                            int M, int N, int K) {
    __shared__ float As[16][64];  // [k][m]
    __shared__ float Bs[16][64];  // [k][n]
    const int tid = threadIdx.x;
    const int tx = tid & 15;      // n-group
    const int ty = tid >> 4;      // m-group
    const int m0 = blockIdx.x * 64;
    const int n0 = blockIdx.y * 64;

    float acc[4][4] = {};

    const int la_m = tid >> 2;          // 0..63
    const int la_k = (tid & 3) * 4;     // 0,4,8,12
    const int lb_k = tid >> 4;          // 0..15
    const int lb_n = (tid & 15) * 4;    // 0..60

    for (int k0 = 0; k0 < K; k0 += 16) {
        float4 av = make_float4(0.f, 0.f, 0.f, 0.f);
        int am = m0 + la_m;
        if (am < M) av = *(const float4*)&A[(long long)am * K + k0 + la_k];
        As[la_k + 0][la_m] = av.x;
        As[la_k + 1][la_m] = av.y;
        As[la_k + 2][la_m] = av.z;
        As[la_k + 3][la_m] = av.w;
        float4 bv = *(const float4*)&B[(long long)(k0 + lb_k) * N + n0 + lb_n];
        *(float4*)&Bs[lb_k][lb_n] = bv;
        __syncthreads();
        #pragma unroll
        for (int kk = 0; kk < 16; kk++) {
            float4 a4 = *(const float4*)&As[kk][ty * 4];
            float4 b4 = *(const float4*)&Bs[kk][tx * 4];
            float a[4] = {a4.x, a4.y, a4.z, a4.w};
            float b[4] = {b4.x, b4.y, b4.z, b4.w};
            #pragma unroll
            for (int i = 0; i < 4; i++)
                #pragma unroll
                for (int j = 0; j < 4; j++)
                    acc[i][j] = fmaf(a[i], b[j], acc[i][j]);
        }
        __syncthreads();
    }

    #pragma unroll
    for (int i = 0; i < 4; i++) {
        int m = m0 + ty * 4 + i;
        if (m >= M) continue;
        float4 cv = make_float4(acc[i][0], acc[i][1], acc[i][2], acc[i][3]);
        if (BIAS) {
            cv.x += bias[n0 + tx * 4 + 0];
            cv.y += bias[n0 + tx * 4 + 1];
            cv.z += bias[n0 + tx * 4 + 2];
            cv.w += bias[n0 + tx * 4 + 3];
        }
        *(float4*)&C[(long long)m * N + n0 + tx * 4] = cv;
    }
}

// ---------------- aggregation: out = relu(seg_sum + self + bias) ----------------
// one wave per node, lane l owns feats [4l, 4l+4)
__global__ __launch_bounds__(256) void aggregate(const float* __restrict__ t,
                                                 const float* __restrict__ dinv,
                                                 const int* __restrict__ row_ptr,
                                                 const int* __restrict__ col_idx,
                                                 const float* __restrict__ bias,
                                                 float* __restrict__ out,
                                                 int N, int do_relu) {
    int wave = threadIdx.x >> 6;
    int lane = threadIdx.x & 63;
    int n = blockIdx.x * 4 + wave;
    if (n >= N) return;

    float dn = dinv[n];
    int r0 = row_ptr[n];
    int r1 = row_ptr[n + 1];

    float4 self = *(const float4*)&t[(long long)n * DH + lane * 4];
    float sn = dn * dn;   // 1/deg
    float4 acc = make_float4(self.x * sn, self.y * sn, self.z * sn, self.w * sn);

    for (int j = r0; j < r1; j++) {
        int s = col_idx[j];
        float w = dinv[s] * dn;
        float4 hv = *(const float4*)&t[(long long)s * DH + lane * 4];
        acc.x = fmaf(w, hv.x, acc.x);
        acc.y = fmaf(w, hv.y, acc.y);
        acc.z = fmaf(w, hv.z, acc.z);
        acc.w = fmaf(w, hv.w, acc.w);
    }
    float4 bv = *(const float4*)&bias[lane * 4];
    acc.x += bv.x; acc.y += bv.y; acc.z += bv.z; acc.w += bv.w;
    if (do_relu) {
        acc.x = fmaxf(acc.x, 0.f);
        acc.y = fmaxf(acc.y, 0.f);
        acc.z = fmaxf(acc.z, 0.f);
        acc.w = fmaxf(acc.w, 0.f);
    }
    *(float4*)&out[(long long)n * DH + lane * 4] = acc;
}

// ---------------- launch ----------------
extern "C" void kernel_launch(void* const* d_in, const int* in_sizes, int n_in,
                              void* d_out, int out_size, void* d_ws, size_t ws_size,
                              hipStream_t stream) {
    const float* x  = (const float*)d_in[0];
    const void*  ei = d_in[1];
    const float* W1 = (const float*)d_in[2];
    const float* b1 = (const float*)d_in[3];
    const float* W2 = (const float*)d_in[4];
    const float* b2 = (const float*)d_in[5];
    const float* Wc = (const float*)d_in[6];
    const float* bc = (const float*)d_in[7];
    float* out = (float*)d_out;

    const int N = in_sizes[0] / DIN;   // 100000
    const int E = in_sizes[1] / 2;     // 800000

    char* ws = (char*)d_ws;
    size_t off = 0;
    auto alloc = [&](size_t bytes) -> void* {
        off = (off + 255) & ~(size_t)255;
        void* p = ws + off;
        off += bytes;
        return p;
    };

    int*   flag      = (int*)alloc(4);
    int*   counts    = (int*)alloc((size_t)N * 4);        // reused as cursor
    int*   row_ptr   = (int*)alloc((size_t)(N + 1) * 4);
    int*   col_idx   = (int*)alloc((size_t)E * 4);
    int*   blocksums = (int*)alloc(1024 * 4);
    float* dinv      = (float*)alloc((size_t)N * 4);
    float* t_buf     = (float*)alloc((size_t)N * DH * 4);
    float* a_buf     = (float*)alloc((size_t)N * DH * 4);

    const int NB = (N + SCAN_ELEMS - 1) / SCAN_ELEMS;

    // 1. dtype detection
    detect_i64<<<1, 256, 0, stream>>>((const unsigned long long*)ei, 1024,
                                      (unsigned long long)N, flag);
    // 2. degrees
    hipMemsetAsync(counts, 0, (size_t)N * 4, stream);
    count_deg<<<(E + 255) / 256, 256, 0, stream>>>(ei, flag, E, counts);
    compute_dinv<<<(N + 255) / 256, 256, 0, stream>>>(counts, dinv, N);
    // 3. CSR build
    scan1<<<NB, SCAN_BLOCK, 0, stream>>>(counts, row_ptr, blocksums, N);
    scan2<<<1, SCAN_BLOCK, 0, stream>>>(blocksums, NB);
    scan3<<<(N + 1 + 255) / 256, 256, 0, stream>>>(row_ptr, blocksums, N, E);
    hipMemsetAsync(counts, 0, (size_t)N * 4, stream);   // counts -> cursor
    fill_csr<<<(E + 255) / 256, 256, 0, stream>>>(ei, flag, E, row_ptr, counts, col_idx);

    const int gM = (N + 63) / 64;
    // 4. layer 1: t = x @ W1 ; a = relu(agg(t) + t/deg + b1)
    gemm<false><<<dim3(gM, DH / 64), 256, 0, stream>>>(x, W1, nullptr, t_buf, N, DH, DIN);
    aggregate<<<(N + 3) / 4, 256, 0, stream>>>(t_buf, dinv, row_ptr, col_idx, b1, a_buf, N, 1);
    // 5. layer 2
    gemm<false><<<dim3(gM, DH / 64), 256, 0, stream>>>(a_buf, W2, nullptr, t_buf, N, DH, DH);
    aggregate<<<(N + 3) / 4, 256, 0, stream>>>(t_buf, dinv, row_ptr, col_idx, b2, a_buf, N, 1);
    // 6. head: out = a @ Wc + bc
    gemm<true><<<dim3(gM, DOUT / 64), 256, 0, stream>>>(a_buf, Wc, bc, out, N, DOUT, DH);
}

// Round 2
// 501.435 us; speedup vs baseline: 1.9484x; 1.9484x over previous
//
#include <hip/hip_runtime.h>
#include <cstdint>

#define DIN 512
#define DH  256
#define DOUT 64

typedef __attribute__((ext_vector_type(8))) short bf16x8;
typedef __attribute__((ext_vector_type(4))) float f32x4;
typedef unsigned int uint32;

__device__ __forceinline__ unsigned short f2bf(float f) {
    uint32 u = __float_as_uint(f);
    u += 0x7fff + ((u >> 16) & 1);          // RNE
    return (unsigned short)(u >> 16);
}
__device__ __forceinline__ float bf2f(unsigned short h) {
    return __uint_as_float(((uint32)h) << 16);
}

// ---------------- edge_index dtype detection ----------------
__global__ void detect_i64(const unsigned long long* ei, int n_check,
                           unsigned long long bound, int* flag) {
    __shared__ int ok;
    if (threadIdx.x == 0) ok = 1;
    __syncthreads();
    int bad = 0;
    for (int i = threadIdx.x; i < n_check; i += blockDim.x) {
        if (ei[i] >= bound) bad = 1;
    }
    if (bad) ok = 0;
    __syncthreads();
    if (threadIdx.x == 0) *flag = ok;
}

__device__ __forceinline__ int get_idx(const void* ei, int is64, int pos) {
    if (is64) return (int)((const long long*)ei)[pos];
    return ((const int*)ei)[pos];
}

// ---------------- degree count / dinv ----------------
__global__ void count_deg(const void* ei, const int* flag, int E, int* counts) {
    const int is64 = *flag;
    int e = blockIdx.x * blockDim.x + threadIdx.x;
    if (e >= E) return;
    int d = get_idx(ei, is64, E + e);
    atomicAdd(&counts[d], 1);
}

__global__ void compute_dinv(const int* counts, float* dinv, int N) {
    int i = blockIdx.x * blockDim.x + threadIdx.x;
    if (i < N) dinv[i] = rsqrtf((float)counts[i] + 1.0f);
}

// ---------------- exclusive scan ----------------
#define SCAN_BLOCK 256
#define SCAN_ELEMS 1024

__global__ void scan1(const int* counts, int* out, int* blocksums, int N) {
    __shared__ int sh[SCAN_BLOCK];
    int base = blockIdx.x * SCAN_ELEMS;
    int t = threadIdx.x;
    int v[4];
    int s = 0;
    #pragma unroll
    for (int j = 0; j < 4; j++) {
        int idx = base + t * 4 + j;
        v[j] = (idx < N) ? counts[idx] : 0;
        s += v[j];
    }
    sh[t] = s;
    __syncthreads();
    for (int off = 1; off < SCAN_BLOCK; off <<= 1) {
        int x = (t >= off) ? sh[t - off] : 0;
        __syncthreads();
        sh[t] += x;
        __syncthreads();
    }
    int run = (t == 0) ? 0 : sh[t - 1];
    #pragma unroll
    for (int j = 0; j < 4; j++) {
        int idx = base + t * 4 + j;
        if (idx < N) out[idx] = run;
        run += v[j];
    }
    if (t == SCAN_BLOCK - 1) blocksums[blockIdx.x] = sh[t];
}

__global__ void scan2(int* blocksums, int NB) {
    __shared__ int sh[SCAN_BLOCK];
    int t = threadIdx.x;
    sh[t] = (t < NB) ? blocksums[t] : 0;
    __syncthreads();
    for (int off = 1; off < SCAN_BLOCK; off <<= 1) {
        int x = (t >= off) ? sh[t - off] : 0;
        __syncthreads();
        sh[t] += x;
        __syncthreads();
    }
    if (t < NB) blocksums[t] = (t == 0) ? 0 : sh[t - 1];
}

__global__ void scan3(int* row_ptr, const int* blocksums, int N, int E) {
    int i = blockIdx.x * blockDim.x + threadIdx.x;
    if (i < N) row_ptr[i] += blocksums[i / SCAN_ELEMS];
    if (i == N) row_ptr[N] = E;
}

// ---------------- CSR fill ----------------
__global__ void fill_csr(const void* ei, const int* flag, int E,
                         const int* row_ptr, int* cursor, int* col_idx) {
    const int is64 = *flag;
    int e = blockIdx.x * blockDim.x + threadIdx.x;
    if (e >= E) return;
    int d = get_idx(ei, is64, E + e);
    int s = get_idx(ei, is64, e);
    int pos = row_ptr[d] + atomicAdd(&cursor[d], 1);
    col_idx[pos] = s;
}

// ---------------- weight transpose+convert: W[K][Nw] f32 -> Bt[Nw][K] bf16 ----------------
__global__ void transpose_w(const float* __restrict__ W, unsigned short* __restrict__ Bt,
                            int K, int Nw) {
    int i = blockIdx.x * blockDim.x + threadIdx.x;
    if (i >= K * Nw) return;
    int k = i / Nw, n = i % Nw;
    Bt[(size_t)n * K + k] = f2bf(W[i]);
}

// ---------------- MFMA GEMM: C[M,N]=A[M,K]*Bt[N,K]^T, bf16 out ----------------
// BM=128 BN=128 BK=64, 256 threads (4 waves, 2x2), m97 structure.
template <bool A_FP32>
__global__ __launch_bounds__(256) void gemm_mfma(const void* __restrict__ Ap,
                                                 const unsigned short* __restrict__ Bt,
                                                 unsigned short* __restrict__ C,
                                                 int M, int N, int K) {
    __shared__ unsigned short lds[16384];   // As[128][64] | Bs[128][64]
    unsigned short* As = lds;
    unsigned short* Bs = lds + 8192;
    const int tid = threadIdx.x;
    const int w = tid >> 6, l = tid & 63;
    const int m0 = blockIdx.x * 128;
    const int n0 = blockIdx.y * 128;
    const int wr = w >> 1, wc = w & 1;

    f32x4 acc[4][4] = {};

    for (int k0 = 0; k0 < K; k0 += 64) {
        // ---- stage B (global_load_lds, 16B) ----
        #pragma unroll
        for (int i = 0; i < 4; i++) {
            int row = i * 32 + w * 8 + (l >> 3);
            const unsigned short* src = Bt + (size_t)(n0 + row) * K + k0 + (l & 7) * 8;
            unsigned short* dst = Bs + row * 64 + (l & 7) * 8;
            __builtin_amdgcn_global_load_lds(
                (const __attribute__((address_space(1))) uint32*)src,
                (__attribute__((address_space(3))) uint32*)dst, 16, 0, 0);
        }
        // ---- stage A ----
        if (A_FP32) {
            const float* Af = (const float*)Ap;
            #pragma unroll
            for (int i = 0; i < 8; i++) {
                int row = i * 16 + (tid >> 4);
                int rg = m0 + row; if (rg > M - 1) rg = M - 1;
                int c4 = (tid & 15) * 4;
                float4 v = *(const float4*)(Af + (size_t)rg * K + k0 + c4);
                ushort4 h;
                h.x = f2bf(v.x); h.y = f2bf(v.y); h.z = f2bf(v.z); h.w = f2bf(v.w);
                *(ushort4*)(As + row * 64 + c4) = h;
            }
        } else {
            const unsigned short* Ab = (const unsigned short*)Ap;
            #pragma unroll
            for (int i = 0; i < 4; i++) {
                int row = i * 32 + w * 8 + (l >> 3);
                int rg = m0 + row; if (rg > M - 1) rg = M - 1;
                const unsigned short* src = Ab + (size_t)rg * K + k0 + (l & 7) * 8;
                unsigned short* dst = As + row * 64 + (l & 7) * 8;
                __builtin_amdgcn_global_load_lds(
                    (const __attribute__((address_space(1))) uint32*)src,
                    (__attribute__((address_space(3))) uint32*)dst, 16, 0, 0);
            }
        }
        __syncthreads();
        // ---- compute ----
        #pragma unroll
        for (int ks = 0; ks < 2; ks++) {
            bf16x8 a[4], b[4];
            #pragma unroll
            for (int m = 0; m < 4; m++)
                a[m] = *(const bf16x8*)(As + (wr * 64 + m * 16 + (l & 15)) * 64 + ks * 32 + (l >> 4) * 8);
            #pragma unroll
            for (int n = 0; n < 4; n++)
                b[n] = *(const bf16x8*)(Bs + (wc * 64 + n * 16 + (l & 15)) * 64 + ks * 32 + (l >> 4) * 8);
            #pragma unroll
            for (int m = 0; m < 4; m++)
                #pragma unroll
                for (int n = 0; n < 4; n++)
                    acc[m][n] = __builtin_amdgcn_mfma_f32_16x16x32_bf16(a[m], b[n], acc[m][n], 0, 0, 0);
        }
        __syncthreads();
    }

    // ---- epilogue: fragments -> LDS (bf16) -> coalesced 16B stores ----
    unsigned short* ep = lds + w * 4096;    // 64x64 per-wave region
    #pragma unroll
    for (int m = 0; m < 4; m++)
        #pragma unroll
        for (int n = 0; n < 4; n++)
            #pragma unroll
            for (int r = 0; r < 4; r++)
                ep[(m * 16 + (l >> 4) * 4 + r) * 64 + n * 16 + (l & 15)] = f2bf(acc[m][n][r]);
    __syncthreads();
    #pragma unroll
    for (int p = 0; p < 8; p++) {
        int row = p * 8 + (l >> 3);
        int gr = m0 + wr * 64 + row;
        uint4 v = *(const uint4*)(ep + row * 64 + (l & 7) * 8);
        if (gr < M)
            *(uint4*)(C + (size_t)gr * N + n0 + wc * 64 + (l & 7) * 8) = v;
    }
}

// ---------------- head GEMM: out[M,64] = A[M,256]*Bt[64,256]^T + bias, f32 out ----------------
__global__ __launch_bounds__(256) void gemm_head(const unsigned short* __restrict__ A,
                                                 const unsigned short* __restrict__ Bt,
                                                 const float* __restrict__ bias,
                                                 float* __restrict__ out, int M) {
    __shared__ unsigned short As[128 * 64];
    __shared__ unsigned short Bs[64 * 64];
    const int tid = threadIdx.x;
    const int w = tid >> 6, l = tid & 63;
    const int m0 = blockIdx.x * 128;
    const int wr = w >> 1, wc = w & 1;
    f32x4 acc[4][2] = {};

    for (int k0 = 0; k0 < 256; k0 += 64) {
        #pragma unroll
        for (int i = 0; i < 4; i++) {
            int row = i * 32 + w * 8 + (l >> 3);
            int rg = m0 + row; if (rg > M - 1) rg = M - 1;
            __builtin_amdgcn_global_load_lds(
                (const __attribute__((address_space(1))) uint32*)(A + (size_t)rg * 256 + k0 + (l & 7) * 8),
                (__attribute__((address_space(3))) uint32*)(As + row * 64 + (l & 7) * 8), 16, 0, 0);
        }
        #pragma unroll
        for (int i = 0; i < 2; i++) {
            int row = i * 32 + w * 8 + (l >> 3);
            __builtin_amdgcn_global_load_lds(
                (const __attribute__((address_space(1))) uint32*)(Bt + (size_t)row * 256 + k0 + (l & 7) * 8),
                (__attribute__((address_space(3))) uint32*)(Bs + row * 64 + (l & 7) * 8), 16, 0, 0);
        }
        __syncthreads();
        #pragma unroll
        for (int ks = 0; ks < 2; ks++) {
            bf16x8 a[4], b[2];
            #pragma unroll
            for (int m = 0; m < 4; m++)
                a[m] = *(const bf16x8*)(As + (wr * 64 + m * 16 + (l & 15)) * 64 + ks * 32 + (l >> 4) * 8);
            #pragma unroll
            for (int n = 0; n < 2; n++)
                b[n] = *(const bf16x8*)(Bs + (wc * 32 + n * 16 + (l & 15)) * 64 + ks * 32 + (l >> 4) * 8);
            #pragma unroll
            for (int m = 0; m < 4; m++)
                #pragma unroll
                for (int n = 0; n < 2; n++)
                    acc[m][n] = __builtin_amdgcn_mfma_f32_16x16x32_bf16(a[m], b[n], acc[m][n], 0, 0, 0);
        }
        __syncthreads();
    }
    #pragma unroll
    for (int m = 0; m < 4; m++)
        #pragma unroll
        for (int n = 0; n < 2; n++)
            #pragma unroll
            for (int r = 0; r < 4; r++) {
                int gr = m0 + wr * 64 + m * 16 + (l >> 4) * 4 + r;
                int col = wc * 32 + n * 16 + (l & 15);
                if (gr < M) out[(size_t)gr * 64 + col] = acc[m][n][r] + bias[col];
            }
}

// ---------------- aggregation (bf16 in/out, f32 accum) ----------------
__global__ __launch_bounds__(256) void aggregate_bf(const unsigned short* __restrict__ t,
                                                    const float* __restrict__ dinv,
                                                    const int* __restrict__ row_ptr,
                                                    const int* __restrict__ col_idx,
                                                    const float* __restrict__ bias,
                                                    unsigned short* __restrict__ outb,
                                                    int N) {
    int wave = threadIdx.x >> 6;
    int lane = threadIdx.x & 63;
    int n = blockIdx.x * 4 + wave;
    if (n >= N) return;

    float dn = dinv[n];
    int r0 = row_ptr[n], r1 = row_ptr[n + 1];

    ushort4 sv = *(const ushort4*)(t + (size_t)n * DH + lane * 4);
    float sn = dn * dn;
    float ax = bf2f(sv.x) * sn, ay = bf2f(sv.y) * sn;
    float az = bf2f(sv.z) * sn, aw = bf2f(sv.w) * sn;

    for (int j = r0; j < r1; j++) {
        int s = col_idx[j];
        float wgt = dinv[s] * dn;
        ushort4 hv = *(const ushort4*)(t + (size_t)s * DH + lane * 4);
        ax = fmaf(wgt, bf2f(hv.x), ax);
        ay = fmaf(wgt, bf2f(hv.y), ay);
        az = fmaf(wgt, bf2f(hv.z), az);
        aw = fmaf(wgt, bf2f(hv.w), aw);
    }
    float4 bv = *(const float4*)(bias + lane * 4);
    ax = fmaxf(ax + bv.x, 0.f);
    ay = fmaxf(ay + bv.y, 0.f);
    az = fmaxf(az + bv.z, 0.f);
    aw = fmaxf(aw + bv.w, 0.f);
    ushort4 o;
    o.x = f2bf(ax); o.y = f2bf(ay); o.z = f2bf(az); o.w = f2bf(aw);
    *(ushort4*)(outb + (size_t)n * DH + lane * 4) = o;
}

// ---------------- launch ----------------
extern "C" void kernel_launch(void* const* d_in, const int* in_sizes, int n_in,
                              void* d_out, int out_size, void* d_ws, size_t ws_size,
                              hipStream_t stream) {
    const float* x  = (const float*)d_in[0];
    const void*  ei = d_in[1];
    const float* W1 = (const float*)d_in[2];
    const float* b1 = (const float*)d_in[3];
    const float* W2 = (const float*)d_in[4];
    const float* b2 = (const float*)d_in[5];
    const float* Wc = (const float*)d_in[6];
    const float* bc = (const float*)d_in[7];
    float* out = (float*)d_out;

    const int N = in_sizes[0] / DIN;   // 100000
    const int E = in_sizes[1] / 2;     // 800000

    char* ws = (char*)d_ws;
    size_t off = 0;
    auto alloc = [&](size_t bytes) -> void* {
        off = (off + 255) & ~(size_t)255;
        void* p = ws + off;
        off += bytes;
        return p;
    };

    int*   flag      = (int*)alloc(4);
    int*   counts    = (int*)alloc((size_t)N * 4);
    int*   row_ptr   = (int*)alloc((size_t)(N + 1) * 4);
    int*   col_idx   = (int*)alloc((size_t)E * 4);
    int*   blocksums = (int*)alloc(1024 * 4);
    float* dinv      = (float*)alloc((size_t)N * 4);
    unsigned short* Bt1   = (unsigned short*)alloc((size_t)DH * DIN * 2);
    unsigned short* Bt2   = (unsigned short*)alloc((size_t)DH * DH * 2);
    unsigned short* Btc   = (unsigned short*)alloc((size_t)DOUT * DH * 2);
    unsigned short* t_buf = (unsigned short*)alloc((size_t)N * DH * 2);
    unsigned short* a_buf = (unsigned short*)alloc((size_t)N * DH * 2);

    const int NB = (N + SCAN_ELEMS - 1) / SCAN_ELEMS;
    const int gM = (N + 127) / 128;

    // dtype detection + weight prep (independent)
    detect_i64<<<1, 256, 0, stream>>>((const unsigned long long*)ei, 1024,
                                      (unsigned long long)N, flag);
    transpose_w<<<(DIN * DH + 255) / 256, 256, 0, stream>>>(W1, Bt1, DIN, DH);
    transpose_w<<<(DH * DH + 255) / 256, 256, 0, stream>>>(W2, Bt2, DH, DH);
    transpose_w<<<(DH * DOUT + 255) / 256, 256, 0, stream>>>(Wc, Btc, DH, DOUT);

    // degrees + CSR
    hipMemsetAsync(counts, 0, (size_t)N * 4, stream);
    count_deg<<<(E + 255) / 256, 256, 0, stream>>>(ei, flag, E, counts);
    compute_dinv<<<(N + 255) / 256, 256, 0, stream>>>(counts, dinv, N);
    scan1<<<NB, SCAN_BLOCK, 0, stream>>>(counts, row_ptr, blocksums, N);
    scan2<<<1, SCAN_BLOCK, 0, stream>>>(blocksums, NB);
    scan3<<<(N + 1 + 255) / 256, 256, 0, stream>>>(row_ptr, blocksums, N, E);
    hipMemsetAsync(counts, 0, (size_t)N * 4, stream);
    fill_csr<<<(E + 255) / 256, 256, 0, stream>>>(ei, flag, E, row_ptr, counts, col_idx);

    // layer 1
    gemm_mfma<true><<<dim3(gM, DH / 128), 256, 0, stream>>>(x, Bt1, t_buf, N, DH, DIN);
    aggregate_bf<<<(N + 3) / 4, 256, 0, stream>>>(t_buf, dinv, row_ptr, col_idx, b1, a_buf, N);
    // layer 2
    gemm_mfma<false><<<dim3(gM, DH / 128), 256, 0, stream>>>(a_buf, Bt2, t_buf, N, DH, DH);
    aggregate_bf<<<(N + 3) / 4, 256, 0, stream>>>(t_buf, dinv, row_ptr, col_idx, b2, a_buf, N);
    // head
    gemm_head<<<gM, 256, 0, stream>>>(a_buf, Btc, bc, out, N);
}

// Round 3
// 411.244 us; speedup vs baseline: 2.3757x; 1.2193x over previous
//
#include <hip/hip_runtime.h>
#include <cstdint>

#define DIN 512
#define DH  256
#define DOUT 64

typedef __attribute__((ext_vector_type(8))) short bf16x8;
typedef __attribute__((ext_vector_type(4))) float f32x4;
typedef unsigned int uint32;

__device__ __forceinline__ unsigned short f2bf(float f) {
    uint32 u = __float_as_uint(f);
    u += 0x7fff + ((u >> 16) & 1);          // RNE
    return (unsigned short)(u >> 16);
}
__device__ __forceinline__ float bf2f(unsigned short h) {
    return __uint_as_float(((uint32)h) << 16);
}
__device__ __forceinline__ float bflo(uint32 u) { return __uint_as_float(u << 16); }
__device__ __forceinline__ float bfhi(uint32 u) { return __uint_as_float(u & 0xffff0000u); }

// ---------------- edge_index dtype detection ----------------
__global__ void detect_i64(const unsigned long long* ei, int n_check,
                           unsigned long long bound, int* flag) {
    __shared__ int ok;
    if (threadIdx.x == 0) ok = 1;
    __syncthreads();
    int bad = 0;
    for (int i = threadIdx.x; i < n_check; i += blockDim.x) {
        if (ei[i] >= bound) bad = 1;
    }
    if (bad) ok = 0;
    __syncthreads();
    if (threadIdx.x == 0) *flag = ok;
}

__device__ __forceinline__ int get_idx(const void* ei, int is64, int pos) {
    if (is64) return (int)((const long long*)ei)[pos];
    return ((const int*)ei)[pos];
}

// ---------------- degree count / dinv ----------------
__global__ void count_deg(const void* ei, const int* flag, int E, int* counts) {
    const int is64 = *flag;
    int e = blockIdx.x * blockDim.x + threadIdx.x;
    if (e >= E) return;
    int d = get_idx(ei, is64, E + e);
    atomicAdd(&counts[d], 1);
}

__global__ void compute_dinv(const int* counts, float* dinv, int N) {
    int i = blockIdx.x * blockDim.x + threadIdx.x;
    if (i < N) dinv[i] = rsqrtf((float)counts[i] + 1.0f);
}

// ---------------- exclusive scan ----------------
#define SCAN_BLOCK 256
#define SCAN_ELEMS 1024

__global__ void scan1(const int* counts, int* out, int* blocksums, int N) {
    __shared__ int sh[SCAN_BLOCK];
    int base = blockIdx.x * SCAN_ELEMS;
    int t = threadIdx.x;
    int v[4];
    int s = 0;
    #pragma unroll
    for (int j = 0; j < 4; j++) {
        int idx = base + t * 4 + j;
        v[j] = (idx < N) ? counts[idx] : 0;
        s += v[j];
    }
    sh[t] = s;
    __syncthreads();
    for (int off = 1; off < SCAN_BLOCK; off <<= 1) {
        int x = (t >= off) ? sh[t - off] : 0;
        __syncthreads();
        sh[t] += x;
        __syncthreads();
    }
    int run = (t == 0) ? 0 : sh[t - 1];
    #pragma unroll
    for (int j = 0; j < 4; j++) {
        int idx = base + t * 4 + j;
        if (idx < N) out[idx] = run;
        run += v[j];
    }
    if (t == SCAN_BLOCK - 1) blocksums[blockIdx.x] = sh[t];
}

__global__ void scan2(int* blocksums, int NB) {
    __shared__ int sh[SCAN_BLOCK];
    int t = threadIdx.x;
    sh[t] = (t < NB) ? blocksums[t] : 0;
    __syncthreads();
    for (int off = 1; off < SCAN_BLOCK; off <<= 1) {
        int x = (t >= off) ? sh[t - off] : 0;
        __syncthreads();
        sh[t] += x;
        __syncthreads();
    }
    if (t < NB) blocksums[t] = (t == 0) ? 0 : sh[t - 1];
}

__global__ void scan3(int* row_ptr, const int* blocksums, int N, int E) {
    int i = blockIdx.x * blockDim.x + threadIdx.x;
    if (i < N) row_ptr[i] += blocksums[i / SCAN_ELEMS];
    if (i == N) row_ptr[N] = E;
}

// ---------------- CSR fill (+ per-edge weight) ----------------
__global__ void fill_csr(const void* ei, const int* flag, int E,
                         const int* row_ptr, int* cursor, int* col_idx,
                         const float* dinv, float* edge_w) {
    const int is64 = *flag;
    int e = blockIdx.x * blockDim.x + threadIdx.x;
    if (e >= E) return;
    int d = get_idx(ei, is64, E + e);
    int s = get_idx(ei, is64, e);
    int pos = row_ptr[d] + atomicAdd(&cursor[d], 1);
    col_idx[pos] = s;
    edge_w[pos] = dinv[s] * dinv[d];
}

// ---------------- weight transpose+convert: W[K][Nw] f32 -> Bt[Nw][K] bf16 ----------------
__global__ void transpose_w(const float* __restrict__ W, unsigned short* __restrict__ Bt,
                            int K, int Nw) {
    int i = blockIdx.x * blockDim.x + threadIdx.x;
    if (i >= K * Nw) return;
    int k = i / Nw, n = i % Nw;
    Bt[(size_t)n * K + k] = f2bf(W[i]);
}

// ---------------- MFMA GEMM: C[M,256]=A[M,K]*Bt[256,K]^T, bf16 out ----------------
// BM=128 BN=256 BK=64, 512 threads (8 waves, 2x4). A is read exactly once.
template <bool A_FP32>
__global__ __launch_bounds__(512) void gemm_mfma(const void* __restrict__ Ap,
                                                 const unsigned short* __restrict__ Bt,
                                                 unsigned short* __restrict__ C,
                                                 int M, int K) {
    __shared__ unsigned short lds[24576];   // As[128][64] | Bs[256][64]
    unsigned short* As = lds;
    unsigned short* Bs = lds + 8192;
    const int tid = threadIdx.x;
    const int w = tid >> 6, l = tid & 63;
    const int m0 = blockIdx.x * 128;
    const int wr = w >> 2, wc = w & 3;

    f32x4 acc[4][4] = {};

    for (int k0 = 0; k0 < K; k0 += 64) {
        // ---- stage B: 256x64 bf16 via global_load_lds 16B ----
        #pragma unroll
        for (int i = 0; i < 4; i++) {
            int row = i * 64 + (tid >> 3);
            const unsigned short* src = Bt + (size_t)row * K + k0 + (tid & 7) * 8;
            unsigned short* dst = Bs + row * 64 + (tid & 7) * 8;
            __builtin_amdgcn_global_load_lds(
                (const __attribute__((address_space(1))) uint32*)src,
                (__attribute__((address_space(3))) uint32*)dst, 16, 0, 0);
        }
        // ---- stage A: 128x64 ----
        if (A_FP32) {
            const float* Af = (const float*)Ap;
            #pragma unroll
            for (int i = 0; i < 4; i++) {
                int row = i * 32 + (tid >> 4);
                int rg = m0 + row; if (rg > M - 1) rg = M - 1;
                int c4 = (tid & 15) * 4;
                float4 v = *(const float4*)(Af + (size_t)rg * K + k0 + c4);
                ushort4 h;
                h.x = f2bf(v.x); h.y = f2bf(v.y); h.z = f2bf(v.z); h.w = f2bf(v.w);
                *(ushort4*)(As + row * 64 + c4) = h;
            }
        } else {
            const unsigned short* Ab = (const unsigned short*)Ap;
            #pragma unroll
            for (int i = 0; i < 2; i++) {
                int row = i * 64 + (tid >> 3);
                int rg = m0 + row; if (rg > M - 1) rg = M - 1;
                const unsigned short* src = Ab + (size_t)rg * K + k0 + (tid & 7) * 8;
                unsigned short* dst = As + row * 64 + (tid & 7) * 8;
                __builtin_amdgcn_global_load_lds(
                    (const __attribute__((address_space(1))) uint32*)src,
                    (__attribute__((address_space(3))) uint32*)dst, 16, 0, 0);
            }
        }
        __syncthreads();
        // ---- compute ----
        #pragma unroll
        for (int ks = 0; ks < 2; ks++) {
            bf16x8 a[4], b[4];
            #pragma unroll
            for (int m = 0; m < 4; m++)
                a[m] = *(const bf16x8*)(As + (wr * 64 + m * 16 + (l & 15)) * 64 + ks * 32 + (l >> 4) * 8);
            #pragma unroll
            for (int n = 0; n < 4; n++)
                b[n] = *(const bf16x8*)(Bs + (wc * 64 + n * 16 + (l & 15)) * 64 + ks * 32 + (l >> 4) * 8);
            #pragma unroll
            for (int m = 0; m < 4; m++)
                #pragma unroll
                for (int n = 0; n < 4; n++)
                    acc[m][n] = __builtin_amdgcn_mfma_f32_16x16x32_bf16(a[m], b[n], acc[m][n], 0, 0, 0);
        }
        __syncthreads();
    }

    // ---- epilogue: two 4-wave phases through LDS, then 16B coalesced stores ----
    unsigned short* ep = lds + (w & 3) * 4096;   // 64x64 bf16 region per wave
    #pragma unroll
    for (int ph = 0; ph < 2; ph++) {
        if ((w >> 2) == ph) {
            #pragma unroll
            for (int m = 0; m < 4; m++)
                #pragma unroll
                for (int n = 0; n < 4; n++)
                    #pragma unroll
                    for (int r = 0; r < 4; r++)
                        ep[(m * 16 + (l >> 4) * 4 + r) * 64 + n * 16 + (l & 15)] = f2bf(acc[m][n][r]);
        }
        __syncthreads();
        if ((w >> 2) == ph) {
            #pragma unroll
            for (int p = 0; p < 8; p++) {
                int row = p * 8 + (l >> 3);
                int gr = m0 + wr * 64 + row;
                uint4 v = *(const uint4*)(ep + row * 64 + (l & 7) * 8);
                if (gr < M)
                    *(uint4*)(C + (size_t)gr * 256 + wc * 64 + (l & 7) * 8) = v;
            }
        }
        __syncthreads();
    }
}

// ---------------- head GEMM: out[M,64] = A[M,256]*Bt[64,256]^T + bias, f32 out ----------------
__global__ __launch_bounds__(256) void gemm_head(const unsigned short* __restrict__ A,
                                                 const unsigned short* __restrict__ Bt,
                                                 const float* __restrict__ bias,
                                                 float* __restrict__ out, int M) {
    __shared__ unsigned short As[128 * 64];
    __shared__ unsigned short Bs[64 * 64];
    const int tid = threadIdx.x;
    const int w = tid >> 6, l = tid & 63;
    const int m0 = blockIdx.x * 128;
    const int wr = w >> 1, wc = w & 1;
    f32x4 acc[4][2] = {};

    for (int k0 = 0; k0 < 256; k0 += 64) {
        #pragma unroll
        for (int i = 0; i < 4; i++) {
            int row = i * 32 + w * 8 + (l >> 3);
            int rg = m0 + row; if (rg > M - 1) rg = M - 1;
            __builtin_amdgcn_global_load_lds(
                (const __attribute__((address_space(1))) uint32*)(A + (size_t)rg * 256 + k0 + (l & 7) * 8),
                (__attribute__((address_space(3))) uint32*)(As + row * 64 + (l & 7) * 8), 16, 0, 0);
        }
        #pragma unroll
        for (int i = 0; i < 2; i++) {
            int row = i * 32 + w * 8 + (l >> 3);
            __builtin_amdgcn_global_load_lds(
                (const __attribute__((address_space(1))) uint32*)(Bt + (size_t)row * 256 + k0 + (l & 7) * 8),
                (__attribute__((address_space(3))) uint32*)(Bs + row * 64 + (l & 7) * 8), 16, 0, 0);
        }
        __syncthreads();
        #pragma unroll
        for (int ks = 0; ks < 2; ks++) {
            bf16x8 a[4], b[2];
            #pragma unroll
            for (int m = 0; m < 4; m++)
                a[m] = *(const bf16x8*)(As + (wr * 64 + m * 16 + (l & 15)) * 64 + ks * 32 + (l >> 4) * 8);
            #pragma unroll
            for (int n = 0; n < 2; n++)
                b[n] = *(const bf16x8*)(Bs + (wc * 32 + n * 16 + (l & 15)) * 64 + ks * 32 + (l >> 4) * 8);
            #pragma unroll
            for (int m = 0; m < 4; m++)
                #pragma unroll
                for (int n = 0; n < 2; n++)
                    acc[m][n] = __builtin_amdgcn_mfma_f32_16x16x32_bf16(a[m], b[n], acc[m][n], 0, 0, 0);
        }
        __syncthreads();
    }
    #pragma unroll
    for (int m = 0; m < 4; m++)
        #pragma unroll
        for (int n = 0; n < 2; n++)
            #pragma unroll
            for (int r = 0; r < 4; r++) {
                int gr = m0 + wr * 64 + m * 16 + (l >> 4) * 4 + r;
                int col = wc * 32 + n * 16 + (l & 15);
                if (gr < M) out[(size_t)gr * 64 + col] = acc[m][n][r] + bias[col];
            }
}

// ---------------- aggregation: 2 nodes/wave, 16B lanes, 4x edge unroll ----------------
#define ACC8(v, wgt)                                    \
    do {                                                \
        acc[0] = fmaf(wgt, bflo(v.x), acc[0]);          \
        acc[1] = fmaf(wgt, bfhi(v.x), acc[1]);          \
        acc[2] = fmaf(wgt, bflo(v.y), acc[2]);          \
        acc[3] = fmaf(wgt, bfhi(v.y), acc[3]);          \
        acc[4] = fmaf(wgt, bflo(v.z), acc[4]);          \
        acc[5] = fmaf(wgt, bfhi(v.z), acc[5]);          \
        acc[6] = fmaf(wgt, bflo(v.w), acc[6]);          \
        acc[7] = fmaf(wgt, bfhi(v.w), acc[7]);          \
    } while (0)

__global__ __launch_bounds__(256) void aggregate_bf(const unsigned short* __restrict__ t,
                                                    const float* __restrict__ dinv,
                                                    const int* __restrict__ row_ptr,
                                                    const int* __restrict__ col_idx,
                                                    const float* __restrict__ edge_w,
                                                    const float* __restrict__ bias,
                                                    unsigned short* __restrict__ outb,
                                                    int N) {
    int wave = threadIdx.x >> 6;
    int lane = threadIdx.x & 63;
    int half = lane >> 5;          // which node of the pair
    int sl = lane & 31;            // owns feats [sl*8, sl*8+8)
    int n = blockIdx.x * 8 + wave * 2 + half;
    if (n >= N) return;

    float dn = dinv[n];
    int r0 = row_ptr[n], r1 = row_ptr[n + 1];

    float acc[8];
    {
        uint4 sv = *(const uint4*)(t + (size_t)n * DH + sl * 8);
        float sn = dn * dn;
        acc[0] = bflo(sv.x) * sn; acc[1] = bfhi(sv.x) * sn;
        acc[2] = bflo(sv.y) * sn; acc[3] = bfhi(sv.y) * sn;
        acc[4] = bflo(sv.z) * sn; acc[5] = bfhi(sv.z) * sn;
        acc[6] = bflo(sv.w) * sn; acc[7] = bfhi(sv.w) * sn;
    }

    int j = r0;
    for (; j + 4 <= r1; j += 4) {
        int s0 = col_idx[j + 0], s1 = col_idx[j + 1];
        int s2 = col_idx[j + 2], s3 = col_idx[j + 3];
        float w0 = edge_w[j + 0], w1 = edge_w[j + 1];
        float w2 = edge_w[j + 2], w3 = edge_w[j + 3];
        uint4 v0 = *(const uint4*)(t + (size_t)s0 * DH + sl * 8);
        uint4 v1 = *(const uint4*)(t + (size_t)s1 * DH + sl * 8);
        uint4 v2 = *(const uint4*)(t + (size_t)s2 * DH + sl * 8);
        uint4 v3 = *(const uint4*)(t + (size_t)s3 * DH + sl * 8);
        ACC8(v0, w0); ACC8(v1, w1); ACC8(v2, w2); ACC8(v3, w3);
    }
    for (; j < r1; j++) {
        int s = col_idx[j];
        float wgt = edge_w[j];
        uint4 v = *(const uint4*)(t + (size_t)s * DH + sl * 8);
        ACC8(v, wgt);
    }

    float4 b0 = *(const float4*)(bias + sl * 8);
    float4 b1v = *(const float4*)(bias + sl * 8 + 4);
    acc[0] = fmaxf(acc[0] + b0.x, 0.f);  acc[1] = fmaxf(acc[1] + b0.y, 0.f);
    acc[2] = fmaxf(acc[2] + b0.z, 0.f);  acc[3] = fmaxf(acc[3] + b0.w, 0.f);
    acc[4] = fmaxf(acc[4] + b1v.x, 0.f); acc[5] = fmaxf(acc[5] + b1v.y, 0.f);
    acc[6] = fmaxf(acc[6] + b1v.z, 0.f); acc[7] = fmaxf(acc[7] + b1v.w, 0.f);

    uint4 o;
    o.x = (uint32)f2bf(acc[0]) | ((uint32)f2bf(acc[1]) << 16);
    o.y = (uint32)f2bf(acc[2]) | ((uint32)f2bf(acc[3]) << 16);
    o.z = (uint32)f2bf(acc[4]) | ((uint32)f2bf(acc[5]) << 16);
    o.w = (uint32)f2bf(acc[6]) | ((uint32)f2bf(acc[7]) << 16);
    *(uint4*)(outb + (size_t)n * DH + sl * 8) = o;
}

// ---------------- launch ----------------
extern "C" void kernel_launch(void* const* d_in, const int* in_sizes, int n_in,
                              void* d_out, int out_size, void* d_ws, size_t ws_size,
                              hipStream_t stream) {
    const float* x  = (const float*)d_in[0];
    const void*  ei = d_in[1];
    const float* W1 = (const float*)d_in[2];
    const float* b1 = (const float*)d_in[3];
    const float* W2 = (const float*)d_in[4];
    const float* b2 = (const float*)d_in[5];
    const float* Wc = (const float*)d_in[6];
    const float* bc = (const float*)d_in[7];
    float* out = (float*)d_out;

    const int N = in_sizes[0] / DIN;   // 100000
    const int E = in_sizes[1] / 2;     // 800000

    char* ws = (char*)d_ws;
    size_t off = 0;
    auto alloc = [&](size_t bytes) -> void* {
        off = (off + 255) & ~(size_t)255;
        void* p = ws + off;
        off += bytes;
        return p;
    };

    int*   flag      = (int*)alloc(4);
    int*   counts    = (int*)alloc((size_t)N * 4);
    int*   row_ptr   = (int*)alloc((size_t)(N + 1) * 4);
    int*   col_idx   = (int*)alloc((size_t)E * 4);
    float* edge_w    = (float*)alloc((size_t)E * 4);
    int*   blocksums = (int*)alloc(1024 * 4);
    float* dinv      = (float*)alloc((size_t)N * 4);
    unsigned short* Bt1   = (unsigned short*)alloc((size_t)DH * DIN * 2);
    unsigned short* Bt2   = (unsigned short*)alloc((size_t)DH * DH * 2);
    unsigned short* Btc   = (unsigned short*)alloc((size_t)DOUT * DH * 2);
    unsigned short* t_buf = (unsigned short*)alloc((size_t)N * DH * 2);
    unsigned short* a_buf = (unsigned short*)alloc((size_t)N * DH * 2);

    const int NB = (N + SCAN_ELEMS - 1) / SCAN_ELEMS;
    const int gM = (N + 127) / 128;

    // dtype detection + weight prep
    detect_i64<<<1, 256, 0, stream>>>((const unsigned long long*)ei, 1024,
                                      (unsigned long long)N, flag);
    transpose_w<<<(DIN * DH + 255) / 256, 256, 0, stream>>>(W1, Bt1, DIN, DH);
    transpose_w<<<(DH * DH + 255) / 256, 256, 0, stream>>>(W2, Bt2, DH, DH);
    transpose_w<<<(DH * DOUT + 255) / 256, 256, 0, stream>>>(Wc, Btc, DH, DOUT);

    // degrees + CSR (+ per-edge weights)
    hipMemsetAsync(counts, 0, (size_t)N * 4, stream);
    count_deg<<<(E + 255) / 256, 256, 0, stream>>>(ei, flag, E, counts);
    compute_dinv<<<(N + 255) / 256, 256, 0, stream>>>(counts, dinv, N);
    scan1<<<NB, SCAN_BLOCK, 0, stream>>>(counts, row_ptr, blocksums, N);
    scan2<<<1, SCAN_BLOCK, 0, stream>>>(blocksums, NB);
    scan3<<<(N + 1 + 255) / 256, 256, 0, stream>>>(row_ptr, blocksums, N, E);
    hipMemsetAsync(counts, 0, (size_t)N * 4, stream);
    fill_csr<<<(E + 255) / 256, 256, 0, stream>>>(ei, flag, E, row_ptr, counts, col_idx,
                                                  dinv, edge_w);

    // layer 1
    gemm_mfma<true><<<gM, 512, 0, stream>>>(x, Bt1, t_buf, N, DIN);
    aggregate_bf<<<(N + 7) / 8, 256, 0, stream>>>(t_buf, dinv, row_ptr, col_idx, edge_w, b1, a_buf, N);
    // layer 2
    gemm_mfma<false><<<gM, 512, 0, stream>>>(a_buf, Bt2, t_buf, N, DH);
    aggregate_bf<<<(N + 7) / 8, 256, 0, stream>>>(t_buf, dinv, row_ptr, col_idx, edge_w, b2, a_buf, N);
    // head
    gemm_head<<<gM, 256, 0, stream>>>(a_buf, Btc, bc, out, N);
}

// Round 4
// 363.997 us; speedup vs baseline: 2.6840x; 1.1298x over previous
//
#include <hip/hip_runtime.h>
#include <cstdint>

#define DIN 512
#define DH  256
#define DOUT 64

typedef __attribute__((ext_vector_type(8))) short bf16x8;
typedef __attribute__((ext_vector_type(4))) float f32x4;
typedef unsigned int uint32;

__device__ __forceinline__ unsigned short f2bf(float f) {
    uint32 u = __float_as_uint(f);
    u += 0x7fff + ((u >> 16) & 1);          // RNE
    return (unsigned short)(u >> 16);
}
__device__ __forceinline__ float bf2f(unsigned short h) {
    return __uint_as_float(((uint32)h) << 16);
}
__device__ __forceinline__ float bflo(uint32 u) { return __uint_as_float(u << 16); }
__device__ __forceinline__ float bfhi(uint32 u) { return __uint_as_float(u & 0xffff0000u); }
__device__ __forceinline__ uint32 pk2(float lo, float hi) {
    return (uint32)f2bf(lo) | ((uint32)f2bf(hi) << 16);
}

// ---------------- edge_index dtype detection ----------------
__global__ void detect_i64(const unsigned long long* ei, int n_check,
                           unsigned long long bound, int* flag) {
    __shared__ int ok;
    if (threadIdx.x == 0) ok = 1;
    __syncthreads();
    int bad = 0;
    for (int i = threadIdx.x; i < n_check; i += blockDim.x) {
        if (ei[i] >= bound) bad = 1;
    }
    if (bad) ok = 0;
    __syncthreads();
    if (threadIdx.x == 0) *flag = ok;
}

__device__ __forceinline__ int get_idx(const void* ei, int is64, int pos) {
    if (is64) return (int)((const long long*)ei)[pos];
    return ((const int*)ei)[pos];
}

// ---------------- degree count / dinv ----------------
__global__ void count_deg(const void* ei, const int* flag, int E, int* counts) {
    const int is64 = *flag;
    int e = blockIdx.x * blockDim.x + threadIdx.x;
    if (e >= E) return;
    int d = get_idx(ei, is64, E + e);
    atomicAdd(&counts[d], 1);
}

__global__ void compute_dinv(const int* counts, float* dinv, int N) {
    int i = blockIdx.x * blockDim.x + threadIdx.x;
    if (i < N) dinv[i] = rsqrtf((float)counts[i] + 1.0f);
}

// ---------------- exclusive scan ----------------
#define SCAN_BLOCK 256
#define SCAN_ELEMS 1024

__global__ void scan1(const int* counts, int* out, int* blocksums, int N) {
    __shared__ int sh[SCAN_BLOCK];
    int base = blockIdx.x * SCAN_ELEMS;
    int t = threadIdx.x;
    int v[4];
    int s = 0;
    #pragma unroll
    for (int j = 0; j < 4; j++) {
        int idx = base + t * 4 + j;
        v[j] = (idx < N) ? counts[idx] : 0;
        s += v[j];
    }
    sh[t] = s;
    __syncthreads();
    for (int off = 1; off < SCAN_BLOCK; off <<= 1) {
        int x = (t >= off) ? sh[t - off] : 0;
        __syncthreads();
        sh[t] += x;
        __syncthreads();
    }
    int run = (t == 0) ? 0 : sh[t - 1];
    #pragma unroll
    for (int j = 0; j < 4; j++) {
        int idx = base + t * 4 + j;
        if (idx < N) out[idx] = run;
        run += v[j];
    }
    if (t == SCAN_BLOCK - 1) blocksums[blockIdx.x] = sh[t];
}

__global__ void scan2(int* blocksums, int NB) {
    __shared__ int sh[SCAN_BLOCK];
    int t = threadIdx.x;
    sh[t] = (t < NB) ? blocksums[t] : 0;
    __syncthreads();
    for (int off = 1; off < SCAN_BLOCK; off <<= 1) {
        int x = (t >= off) ? sh[t - off] : 0;
        __syncthreads();
        sh[t] += x;
        __syncthreads();
    }
    if (t < NB) blocksums[t] = (t == 0) ? 0 : sh[t - 1];
}

__global__ void scan3(int* row_ptr, const int* blocksums, int N, int E) {
    int i = blockIdx.x * blockDim.x + threadIdx.x;
    if (i < N) row_ptr[i] += blocksums[i / SCAN_ELEMS];
    if (i == N) row_ptr[N] = E;
}

// ---------------- CSR fill (+ per-edge weight) ----------------
__global__ void fill_csr(const void* ei, const int* flag, int E,
                         const int* row_ptr, int* cursor, int* col_idx,
                         const float* dinv, float* edge_w) {
    const int is64 = *flag;
    int e = blockIdx.x * blockDim.x + threadIdx.x;
    if (e >= E) return;
    int d = get_idx(ei, is64, E + e);
    int s = get_idx(ei, is64, e);
    int pos = row_ptr[d] + atomicAdd(&cursor[d], 1);
    col_idx[pos] = s;
    edge_w[pos] = dinv[s] * dinv[d];
}

// ---------------- weight transpose+convert: W[K][Nw] f32 -> Bt[Nw][K] bf16 ----------------
__global__ void transpose_w(const float* __restrict__ W, unsigned short* __restrict__ Bt,
                            int K, int Nw) {
    int i = blockIdx.x * blockDim.x + threadIdx.x;
    if (i >= K * Nw) return;
    int k = i / Nw, n = i % Nw;
    Bt[(size_t)n * K + k] = f2bf(W[i]);
}

// ---------------- MFMA GEMM: C[M,256]=A[M,K]*Bt[256,K]^T, bf16 out ----------------
// BM=64 BN=256 BK=64, 256 threads (4 waves, 1x4). A read exactly once.
// LDS XOR-swizzle (granule ^= row&7): linear gload_lds dest + pre-swizzled
// global source, swizzled ds_read address (rule #21).
template <bool A_FP32>
__global__ __launch_bounds__(256) void gemm_mfma(const void* __restrict__ Ap,
                                                 const unsigned short* __restrict__ Bt,
                                                 unsigned short* __restrict__ C,
                                                 int M, int K) {
    __shared__ unsigned short lds[20480];   // As[64][64] | Bs[256][64] = 40 KB
    unsigned short* As = lds;
    unsigned short* Bs = lds + 4096;
    const int tid = threadIdx.x;
    const int w = tid >> 6, l = tid & 63;
    const int m0 = blockIdx.x * 64;

    f32x4 acc[4][4] = {};

    for (int k0 = 0; k0 < K; k0 += 64) {
        // ---- stage B: 256x64 bf16, source granule pre-swizzled ----
        #pragma unroll
        for (int i = 0; i < 8; i++) {
            int row = i * 32 + (tid >> 3);
            int gq = (tid & 7) ^ (row & 7);
            const unsigned short* src = Bt + (size_t)row * K + k0 + gq * 8;
            unsigned short* dst = Bs + row * 64 + (tid & 7) * 8;
            __builtin_amdgcn_global_load_lds(
                (const __attribute__((address_space(1))) uint32*)src,
                (__attribute__((address_space(3))) uint32*)dst, 16, 0, 0);
        }
        // ---- stage A: 64x64 ----
        if (A_FP32) {
            const float* Af = (const float*)Ap;
            #pragma unroll
            for (int i = 0; i < 2; i++) {
                int row = i * 32 + (tid >> 3);
                int g = tid & 7;
                int rg = m0 + row; if (rg > M - 1) rg = M - 1;
                const float* s = Af + (size_t)rg * K + k0 + g * 8;
                float4 v0 = *(const float4*)s;
                float4 v1 = *(const float4*)(s + 4);
                uint4 o;
                o.x = pk2(v0.x, v0.y); o.y = pk2(v0.z, v0.w);
                o.z = pk2(v1.x, v1.y); o.w = pk2(v1.z, v1.w);
                *(uint4*)(As + row * 64 + ((g ^ (row & 7)) * 8)) = o;
            }
        } else {
            const unsigned short* Ab = (const unsigned short*)Ap;
            #pragma unroll
            for (int i = 0; i < 2; i++) {
                int row = i * 32 + (tid >> 3);
                int gq = (tid & 7) ^ (row & 7);
                int rg = m0 + row; if (rg > M - 1) rg = M - 1;
                const unsigned short* src = Ab + (size_t)rg * K + k0 + gq * 8;
                unsigned short* dst = As + row * 64 + (tid & 7) * 8;
                __builtin_amdgcn_global_load_lds(
                    (const __attribute__((address_space(1))) uint32*)src,
                    (__attribute__((address_space(3))) uint32*)dst, 16, 0, 0);
            }
        }
        __syncthreads();
        // ---- compute (swizzled ds_read) ----
        #pragma unroll
        for (int ks = 0; ks < 2; ks++) {
            bf16x8 a[4], b[4];
            #pragma unroll
            for (int m = 0; m < 4; m++) {
                int arow = m * 16 + (l & 15);
                int ag = (ks * 4 + (l >> 4)) ^ (arow & 7);
                a[m] = *(const bf16x8*)(As + arow * 64 + ag * 8);
            }
            #pragma unroll
            for (int n = 0; n < 4; n++) {
                int brow = w * 64 + n * 16 + (l & 15);
                int bg = (ks * 4 + (l >> 4)) ^ (brow & 7);
                b[n] = *(const bf16x8*)(Bs + brow * 64 + bg * 8);
            }
            #pragma unroll
            for (int m = 0; m < 4; m++)
                #pragma unroll
                for (int n = 0; n < 4; n++)
                    acc[m][n] = __builtin_amdgcn_mfma_f32_16x16x32_bf16(a[m], b[n], acc[m][n], 0, 0, 0);
        }
        __syncthreads();
    }

    // ---- epilogue: per-wave 64x64 region -> coalesced 16B stores ----
    unsigned short* ep = lds + w * 4096;
    #pragma unroll
    for (int m = 0; m < 4; m++)
        #pragma unroll
        for (int n = 0; n < 4; n++)
            #pragma unroll
            for (int r = 0; r < 4; r++)
                ep[(m * 16 + (l >> 4) * 4 + r) * 64 + n * 16 + (l & 15)] = f2bf(acc[m][n][r]);
    __syncthreads();
    #pragma unroll
    for (int p = 0; p < 8; p++) {
        int row = p * 8 + (l >> 3);
        int gr = m0 + row;
        uint4 v = *(const uint4*)(ep + row * 64 + (l & 7) * 8);
        if (gr < M)
            *(uint4*)(C + (size_t)gr * 256 + w * 64 + (l & 7) * 8) = v;
    }
}

// ---------------- head GEMM: out[M,64] = A[M,256]*Bt[64,256]^T + bias, f32 out ----------------
__global__ __launch_bounds__(256) void gemm_head(const unsigned short* __restrict__ A,
                                                 const unsigned short* __restrict__ Bt,
                                                 const float* __restrict__ bias,
                                                 float* __restrict__ out, int M) {
    __shared__ unsigned short As[128 * 64];
    __shared__ unsigned short Bs[64 * 64];
    const int tid = threadIdx.x;
    const int w = tid >> 6, l = tid & 63;
    const int m0 = blockIdx.x * 128;
    const int wr = w >> 1, wc = w & 1;
    f32x4 acc[4][2] = {};

    for (int k0 = 0; k0 < 256; k0 += 64) {
        #pragma unroll
        for (int i = 0; i < 4; i++) {
            int row = i * 32 + (tid >> 3);
            int gq = (tid & 7) ^ (row & 7);
            int rg = m0 + row; if (rg > M - 1) rg = M - 1;
            __builtin_amdgcn_global_load_lds(
                (const __attribute__((address_space(1))) uint32*)(A + (size_t)rg * 256 + k0 + gq * 8),
                (__attribute__((address_space(3))) uint32*)(As + row * 64 + (tid & 7) * 8), 16, 0, 0);
        }
        #pragma unroll
        for (int i = 0; i < 2; i++) {
            int row = i * 32 + (tid >> 3);
            int gq = (tid & 7) ^ (row & 7);
            __builtin_amdgcn_global_load_lds(
                (const __attribute__((address_space(1))) uint32*)(Bt + (size_t)row * 256 + k0 + gq * 8),
                (__attribute__((address_space(3))) uint32*)(Bs + row * 64 + (tid & 7) * 8), 16, 0, 0);
        }
        __syncthreads();
        #pragma unroll
        for (int ks = 0; ks < 2; ks++) {
            bf16x8 a[4], b[2];
            #pragma unroll
            for (int m = 0; m < 4; m++) {
                int arow = wr * 64 + m * 16 + (l & 15);
                int ag = (ks * 4 + (l >> 4)) ^ (arow & 7);
                a[m] = *(const bf16x8*)(As + arow * 64 + ag * 8);
            }
            #pragma unroll
            for (int n = 0; n < 2; n++) {
                int brow = wc * 32 + n * 16 + (l & 15);
                int bg = (ks * 4 + (l >> 4)) ^ (brow & 7);
                b[n] = *(const bf16x8*)(Bs + brow * 64 + bg * 8);
            }
            #pragma unroll
            for (int m = 0; m < 4; m++)
                #pragma unroll
                for (int n = 0; n < 2; n++)
                    acc[m][n] = __builtin_amdgcn_mfma_f32_16x16x32_bf16(a[m], b[n], acc[m][n], 0, 0, 0);
        }
        __syncthreads();
    }
    #pragma unroll
    for (int m = 0; m < 4; m++)
        #pragma unroll
        for (int n = 0; n < 2; n++)
            #pragma unroll
            for (int r = 0; r < 4; r++) {
                int gr = m0 + wr * 64 + m * 16 + (l >> 4) * 4 + r;
                int col = wc * 32 + n * 16 + (l & 15);
                if (gr < M) out[(size_t)gr * 64 + col] = acc[m][n][r] + bias[col];
            }
}

// ---------------- aggregation: 2 nodes/wave, 16B lanes, 4x edge unroll ----------------
#define ACC8(v, wgt)                                    \
    do {                                                \
        acc[0] = fmaf(wgt, bflo(v.x), acc[0]);          \
        acc[1] = fmaf(wgt, bfhi(v.x), acc[1]);          \
        acc[2] = fmaf(wgt, bflo(v.y), acc[2]);          \
        acc[3] = fmaf(wgt, bfhi(v.y), acc[3]);          \
        acc[4] = fmaf(wgt, bflo(v.z), acc[4]);          \
        acc[5] = fmaf(wgt, bfhi(v.z), acc[5]);          \
        acc[6] = fmaf(wgt, bflo(v.w), acc[6]);          \
        acc[7] = fmaf(wgt, bfhi(v.w), acc[7]);          \
    } while (0)

__global__ __launch_bounds__(256) void aggregate_bf(const unsigned short* __restrict__ t,
                                                    const float* __restrict__ dinv,
                                                    const int* __restrict__ row_ptr,
                                                    const int* __restrict__ col_idx,
                                                    const float* __restrict__ edge_w,
                                                    const float* __restrict__ bias,
                                                    unsigned short* __restrict__ outb,
                                                    int N) {
    int wave = threadIdx.x >> 6;
    int lane = threadIdx.x & 63;
    int half = lane >> 5;          // which node of the pair
    int sl = lane & 31;            // owns feats [sl*8, sl*8+8)
    int n = blockIdx.x * 8 + wave * 2 + half;
    if (n >= N) return;

    float dn = dinv[n];
    int r0 = row_ptr[n], r1 = row_ptr[n + 1];

    float acc[8];
    {
        uint4 sv = *(const uint4*)(t + (size_t)n * DH + sl * 8);
        float sn = dn * dn;
        acc[0] = bflo(sv.x) * sn; acc[1] = bfhi(sv.x) * sn;
        acc[2] = bflo(sv.y) * sn; acc[3] = bfhi(sv.y) * sn;
        acc[4] = bflo(sv.z) * sn; acc[5] = bfhi(sv.z) * sn;
        acc[6] = bflo(sv.w) * sn; acc[7] = bfhi(sv.w) * sn;
    }

    int j = r0;
    for (; j + 4 <= r1; j += 4) {
        int s0 = col_idx[j + 0], s1 = col_idx[j + 1];
        int s2 = col_idx[j + 2], s3 = col_idx[j + 3];
        float w0 = edge_w[j + 0], w1 = edge_w[j + 1];
        float w2 = edge_w[j + 2], w3 = edge_w[j + 3];
        uint4 v0 = *(const uint4*)(t + (size_t)s0 * DH + sl * 8);
        uint4 v1 = *(const uint4*)(t + (size_t)s1 * DH + sl * 8);
        uint4 v2 = *(const uint4*)(t + (size_t)s2 * DH + sl * 8);
        uint4 v3 = *(const uint4*)(t + (size_t)s3 * DH + sl * 8);
        ACC8(v0, w0); ACC8(v1, w1); ACC8(v2, w2); ACC8(v3, w3);
    }
    for (; j < r1; j++) {
        int s = col_idx[j];
        float wgt = edge_w[j];
        uint4 v = *(const uint4*)(t + (size_t)s * DH + sl * 8);
        ACC8(v, wgt);
    }

    float4 b0 = *(const float4*)(bias + sl * 8);
    float4 b1v = *(const float4*)(bias + sl * 8 + 4);
    acc[0] = fmaxf(acc[0] + b0.x, 0.f);  acc[1] = fmaxf(acc[1] + b0.y, 0.f);
    acc[2] = fmaxf(acc[2] + b0.z, 0.f);  acc[3] = fmaxf(acc[3] + b0.w, 0.f);
    acc[4] = fmaxf(acc[4] + b1v.x, 0.f); acc[5] = fmaxf(acc[5] + b1v.y, 0.f);
    acc[6] = fmaxf(acc[6] + b1v.z, 0.f); acc[7] = fmaxf(acc[7] + b1v.w, 0.f);

    uint4 o;
    o.x = pk2(acc[0], acc[1]);
    o.y = pk2(acc[2], acc[3]);
    o.z = pk2(acc[4], acc[5]);
    o.w = pk2(acc[6], acc[7]);
    *(uint4*)(outb + (size_t)n * DH + sl * 8) = o;
}

// ---------------- launch ----------------
extern "C" void kernel_launch(void* const* d_in, const int* in_sizes, int n_in,
                              void* d_out, int out_size, void* d_ws, size_t ws_size,
                              hipStream_t stream) {
    const float* x  = (const float*)d_in[0];
    const void*  ei = d_in[1];
    const float* W1 = (const float*)d_in[2];
    const float* b1 = (const float*)d_in[3];
    const float* W2 = (const float*)d_in[4];
    const float* b2 = (const float*)d_in[5];
    const float* Wc = (const float*)d_in[6];
    const float* bc = (const float*)d_in[7];
    float* out = (float*)d_out;

    const int N = in_sizes[0] / DIN;   // 100000
    const int E = in_sizes[1] / 2;     // 800000

    char* ws = (char*)d_ws;
    size_t off = 0;
    auto alloc = [&](size_t bytes) -> void* {
        off = (off + 255) & ~(size_t)255;
        void* p = ws + off;
        off += bytes;
        return p;
    };

    int*   flag      = (int*)alloc(4);
    int*   counts    = (int*)alloc((size_t)N * 4);
    int*   row_ptr   = (int*)alloc((size_t)(N + 1) * 4);
    int*   col_idx   = (int*)alloc((size_t)E * 4);
    float* edge_w    = (float*)alloc((size_t)E * 4);
    int*   blocksums = (int*)alloc(1024 * 4);
    float* dinv      = (float*)alloc((size_t)N * 4);
    unsigned short* Bt1   = (unsigned short*)alloc((size_t)DH * DIN * 2);
    unsigned short* Bt2   = (unsigned short*)alloc((size_t)DH * DH * 2);
    unsigned short* Btc   = (unsigned short*)alloc((size_t)DOUT * DH * 2);
    unsigned short* t_buf = (unsigned short*)alloc((size_t)N * DH * 2);
    unsigned short* a_buf = (unsigned short*)alloc((size_t)N * DH * 2);

    const int NB = (N + SCAN_ELEMS - 1) / SCAN_ELEMS;
    const int gM64  = (N + 63) / 64;
    const int gM128 = (N + 127) / 128;

    // dtype detection + weight prep
    detect_i64<<<1, 256, 0, stream>>>((const unsigned long long*)ei, 1024,
                                      (unsigned long long)N, flag);
    transpose_w<<<(DIN * DH + 255) / 256, 256, 0, stream>>>(W1, Bt1, DIN, DH);
    transpose_w<<<(DH * DH + 255) / 256, 256, 0, stream>>>(W2, Bt2, DH, DH);
    transpose_w<<<(DH * DOUT + 255) / 256, 256, 0, stream>>>(Wc, Btc, DH, DOUT);

    // degrees + CSR (+ per-edge weights)
    hipMemsetAsync(counts, 0, (size_t)N * 4, stream);
    count_deg<<<(E + 255) / 256, 256, 0, stream>>>(ei, flag, E, counts);
    compute_dinv<<<(N + 255) / 256, 256, 0, stream>>>(counts, dinv, N);
    scan1<<<NB, SCAN_BLOCK, 0, stream>>>(counts, row_ptr, blocksums, N);
    scan2<<<1, SCAN_BLOCK, 0, stream>>>(blocksums, NB);
    scan3<<<(N + 1 + 255) / 256, 256, 0, stream>>>(row_ptr, blocksums, N, E);
    hipMemsetAsync(counts, 0, (size_t)N * 4, stream);
    fill_csr<<<(E + 255) / 256, 256, 0, stream>>>(ei, flag, E, row_ptr, counts, col_idx,
                                                  dinv, edge_w);

    // layer 1
    gemm_mfma<true><<<gM64, 256, 0, stream>>>(x, Bt1, t_buf, N, DIN);
    aggregate_bf<<<(N + 7) / 8, 256, 0, stream>>>(t_buf, dinv, row_ptr, col_idx, edge_w, b1, a_buf, N);
    // layer 2
    gemm_mfma<false><<<gM64, 256, 0, stream>>>(a_buf, Bt2, t_buf, N, DH);
    aggregate_bf<<<(N + 7) / 8, 256, 0, stream>>>(t_buf, dinv, row_ptr, col_idx, edge_w, b2, a_buf, N);
    // head
    gemm_head<<<gM128, 256, 0, stream>>>(a_buf, Btc, bc, out, N);
}